// Round 11
// baseline (342.994 us; speedup 1.0000x reference)
//
#include <hip/hip_runtime.h>
#include <hip/hip_bf16.h>

typedef __bf16 bf16_t;
typedef __bf16 bf16x4 __attribute__((ext_vector_type(4)));
typedef __bf16 bf16x8 __attribute__((ext_vector_type(8)));
typedef float f32x4 __attribute__((ext_vector_type(4)));

typedef __attribute__((address_space(1))) unsigned char glob_u8;
typedef __attribute__((address_space(3))) unsigned char lds_u8;

__device__ __forceinline__ void load_lds16(const void* g, void* l) {
    __builtin_amdgcn_global_load_lds((glob_u8*)g, (lds_u8*)l, 16, 0, 0);
}

// ---------------------------------------------------------------------------
// Weight transposes with f32 -> bf16 convert: W[din][dout] -> WT[dout][din]
// ---------------------------------------------------------------------------
__global__ void transpose_qkvw_kernel(const float* __restrict__ wq, const float* __restrict__ wk,
                                      const float* __restrict__ wv, bf16_t* __restrict__ wqkvT)
{
    __shared__ bf16_t tile[64][65];
    int z = blockIdx.z;
    const float* src = (z == 0) ? wq : (z == 1) ? wk : wv;
    bf16_t* dst = wqkvT + (size_t)z * 1048576;
    int rB = blockIdx.y * 64, cB = blockIdx.x * 64;
    int t = threadIdx.x;
#pragma unroll
    for (int i = 0; i < 16; i++) {
        int e = t + i * 256; int r = e >> 6, c = e & 63;
        tile[r][c] = (bf16_t)src[(size_t)(rB + r) * 1024 + cB + c];
    }
    __syncthreads();
#pragma unroll
    for (int i = 0; i < 16; i++) {
        int e = t + i * 256; int r = e >> 6, c = e & 63;
        dst[(size_t)(cB + r) * 1024 + rB + c] = tile[c][r];
    }
}

__global__ void transpose_one_kernel(const float* __restrict__ src, bf16_t* __restrict__ dst)
{
    __shared__ bf16_t tile[64][65];
    int rB = blockIdx.y * 64, cB = blockIdx.x * 64;
    int t = threadIdx.x;
#pragma unroll
    for (int i = 0; i < 16; i++) {
        int e = t + i * 256; int r = e >> 6, c = e & 63;
        tile[r][c] = (bf16_t)src[(size_t)(rB + r) * 1024 + cB + c];
    }
    __syncthreads();
#pragma unroll
    for (int i = 0; i < 16; i++) {
        int e = t + i * 256; int r = e >> 6, c = e & 63;
        dst[(size_t)(cB + r) * 1024 + rB + c] = tile[c][r];
    }
}

__global__ void transpose_small_kernel(const float* __restrict__ s0, const float* __restrict__ s1,
                                       const float* __restrict__ s2,
                                       bf16_t* __restrict__ d0, bf16_t* __restrict__ d1, bf16_t* __restrict__ d2)
{
    int z = blockIdx.x;
    const float* src = (z == 0) ? s0 : (z == 1) ? s1 : s2;
    bf16_t* dst = (z == 0) ? d0 : (z == 1) ? d1 : d2;
    int t = threadIdx.x;
#pragma unroll
    for (int i = 0; i < 16; i++) {
        int e = t + i * 256; int r = e >> 6, c = e & 63;
        dst[c * 64 + r] = (bf16_t)src[r * 64 + c];
    }
}

// ---------------------------------------------------------------------------
// Mask pre-scan: flags[b*1024 + qt*32 + kt] = 1 iff whole 64x64 tile nonzero
// ---------------------------------------------------------------------------
__global__ void maskflags_kernel(const int* __restrict__ mask, int* __restrict__ flags)
{
    int tile = blockIdx.x;              // b*1024 + qt*32 + kt
    int b = tile >> 10, qt = (tile >> 5) & 31, kt = tile & 31;
    int ok = 1;
#pragma unroll
    for (int i = 0; i < 16; i++) {
        int e = threadIdx.x + i * 256; int r = e >> 6, c = e & 63;
        ok &= (mask[((size_t)b * 2048 + qt * 64 + r) * 2048 + kt * 64 + c] != 0) ? 1 : 0;
    }
    ok = __syncthreads_and(ok);
    if (threadIdx.x == 0) flags[tile] = ok;
}

// ---------------------------------------------------------------------------
// QKV GEMM v4: 128x128 C-tile (round-8 best), BK=64 (16 k-iters, 32 MFMAs
// per barrier pair - 2x amortization vs BK=32). Explicit staging, stride 72.
// z<2: C = A*W^T -> [B,H,L,DK].  z==2: operands swapped (C^T) so the
// [B,H,DK,L] store is lane15 = l -> coalesced.
// ---------------------------------------------------------------------------
#define GS2 72   // LDS row stride (bf16) for 64-wide K tile (64+8 pad)

__global__ __launch_bounds__(256, 3) void gemm_qkv_kernel(
    const float* __restrict__ Aq, const float* __restrict__ Ak, const float* __restrict__ Av,
    const bf16_t* __restrict__ WT,
    const float* __restrict__ bq, const float* __restrict__ bk, const float* __restrict__ bv,
    bf16_t* __restrict__ outbase)
{
    __shared__ bf16_t As[128 * GS2];    // 18 KB
    __shared__ bf16_t Bs[128 * GS2];    // 18 KB
    const int z = blockIdx.z;
    const float* A    = (z == 0) ? Aq : (z == 1) ? Ak : Av;
    const bf16_t* Bt  = WT + (size_t)z * 1048576;
    const float* bia  = (z == 0) ? bq : (z == 1) ? bk : bv;
    bf16_t* out = outbase + (size_t)z * 4194304;

    const int t = threadIdx.x;
    const int w = t >> 6, lane = t & 63;
    const int lane15 = lane & 15, quad = lane >> 4;
    const int wr = w >> 1, wc = w & 1;
    const int rowBase = blockIdx.x * 128, colBase = blockIdx.y * 128;

    // staging: thread t -> row t>>1, col-half (t&1)*32 (32 elems = 64B bf16)
    const int sr = t >> 1, sc = (t & 1) * 32;

    f32x4 acc[4][4];
    f32x4 zf = {0.f, 0.f, 0.f, 0.f};
#pragma unroll
    for (int i = 0; i < 4; i++)
#pragma unroll
        for (int j = 0; j < 4; j++) acc[i][j] = zf;

    for (int k0 = 0; k0 < 1024; k0 += 64) {
        // A: 32 f32 -> 32 bf16
        const float4* ap = (const float4*)(A + (size_t)(rowBase + sr) * 1024 + k0 + sc);
        float4 af4[8];
#pragma unroll
        for (int i = 0; i < 8; i++) af4[i] = ap[i];
        // B: 32 bf16 (4x bf16x8)
        const bf16x8* bp = (const bf16x8*)(Bt + (size_t)(colBase + sr) * 1024 + k0 + sc);
        bf16x8 bv8[4];
#pragma unroll
        for (int i = 0; i < 4; i++) bv8[i] = bp[i];
#pragma unroll
        for (int i = 0; i < 4; i++) {
            bf16x8 av;
            av[0] = (bf16_t)af4[i * 2].x;     av[1] = (bf16_t)af4[i * 2].y;
            av[2] = (bf16_t)af4[i * 2].z;     av[3] = (bf16_t)af4[i * 2].w;
            av[4] = (bf16_t)af4[i * 2 + 1].x; av[5] = (bf16_t)af4[i * 2 + 1].y;
            av[6] = (bf16_t)af4[i * 2 + 1].z; av[7] = (bf16_t)af4[i * 2 + 1].w;
            *(bf16x8*)(As + sr * GS2 + sc + i * 8) = av;
            *(bf16x8*)(Bs + sr * GS2 + sc + i * 8) = bv8[i];
        }
        __syncthreads();
#pragma unroll
        for (int kk = 0; kk < 2; kk++) {
            bf16x8 afr[4], bfr[4];
#pragma unroll
            for (int mi = 0; mi < 4; mi++)
                afr[mi] = *(const bf16x8*)(As + (wr * 64 + mi * 16 + lane15) * GS2 + kk * 32 + quad * 8);
#pragma unroll
            for (int ni = 0; ni < 4; ni++)
                bfr[ni] = *(const bf16x8*)(Bs + (wc * 64 + ni * 16 + lane15) * GS2 + kk * 32 + quad * 8);
            if (z < 2) {
#pragma unroll
                for (int mi = 0; mi < 4; mi++)
#pragma unroll
                    for (int ni = 0; ni < 4; ni++)
                        acc[mi][ni] = __builtin_amdgcn_mfma_f32_16x16x32_bf16(afr[mi], bfr[ni], acc[mi][ni], 0, 0, 0);
            } else {    // transposed accumulation for coalesced Vt store
#pragma unroll
                for (int mi = 0; mi < 4; mi++)
#pragma unroll
                    for (int ni = 0; ni < 4; ni++)
                        acc[mi][ni] = __builtin_amdgcn_mfma_f32_16x16x32_bf16(bfr[ni], afr[mi], acc[mi][ni], 0, 0, 0);
            }
        }
        __syncthreads();
    }

    if (z < 2) {
        // C[row=l][col=dout]: col = lane15 -> [B,H,L,DK] store
#pragma unroll
        for (int ni = 0; ni < 4; ni++) {
            int col = colBase + wc * 64 + ni * 16 + lane15;   // dout
            float bias = bia[col];
            int h = col >> 6, dk = col & 63;
#pragma unroll
            for (int mi = 0; mi < 4; mi++) {
#pragma unroll
                for (int r = 0; r < 4; r++) {
                    int row = rowBase + wr * 64 + mi * 16 + quad * 4 + r;
                    int b = row >> 11, l = row & 2047;
                    out[((((size_t)(b * 16 + h)) * 2048 + l) * 64 + dk)] =
                        (bf16_t)(acc[mi][ni][r] + bias);
                }
            }
        }
    } else {
        // C^T[row=dout][col=l]: col = lane15 -> coalesced [B,H,DK,L] store
#pragma unroll
        for (int ni = 0; ni < 4; ni++) {
#pragma unroll
            for (int r = 0; r < 4; r++) {
                int dout = colBase + wc * 64 + ni * 16 + quad * 4 + r;
                float bias = bia[dout];
                int h = dout >> 6, dk = dout & 63;
#pragma unroll
                for (int mi = 0; mi < 4; mi++) {
                    int rowl = rowBase + wr * 64 + mi * 16 + lane15;
                    int b = rowl >> 11, l = rowl & 2047;
                    out[((((size_t)(b * 16 + h)) * 64 + dk) * 2048 + l)] =
                        (bf16_t)(acc[mi][ni][r] + bias);
                }
            }
        }
    }
}

// ---------------------------------------------------------------------------
// Output projection: A (concat) bf16, Bt (woT) bf16, out f32.
// 128x64 tile -> 512 blocks. m97 DMA staging, unpadded layout.
// ---------------------------------------------------------------------------
__global__ __launch_bounds__(256, 2) void gemm_out_kernel(
    const bf16_t* __restrict__ A, const bf16_t* __restrict__ Bt,
    const float* __restrict__ bia, float* __restrict__ out)
{
    __shared__ bf16_t As[128 * 32];     // 8 KB
    __shared__ bf16_t Bs[64 * 32];      // 4 KB
    const int t = threadIdx.x;
    const int w = t >> 6, lane = t & 63;
    const int lane15 = lane & 15, quad = lane >> 4;
    const int wr = w >> 1, wc = w & 1;
    const int rowBase = blockIdx.x * 128, colBase = blockIdx.y * 64;

    const int brow = lane >> 2, bcol = (lane & 3) * 8;  // bf16 chunk map

    f32x4 acc[4][2];
    f32x4 zf = {0.f, 0.f, 0.f, 0.f};
#pragma unroll
    for (int i = 0; i < 4; i++)
#pragma unroll
        for (int j = 0; j < 2; j++) acc[i][j] = zf;

    for (int k0 = 0; k0 < 1024; k0 += 32) {
#pragma unroll
        for (int j = 0; j < 2; j++) {   // 2 A-chunks per wave
            int chunk = w * 2 + j;
            load_lds16(A + (size_t)(rowBase + chunk * 16 + brow) * 1024 + k0 + bcol,
                       (char*)As + chunk * 1024);
        }
        {                               // 1 B-chunk per wave
            int chunk = w;
            load_lds16(Bt + (size_t)(colBase + chunk * 16 + brow) * 1024 + k0 + bcol,
                       (char*)Bs + chunk * 1024);
        }
        __syncthreads();
        bf16x8 afr[4], bfr[2];
#pragma unroll
        for (int mi = 0; mi < 4; mi++)
            afr[mi] = *(const bf16x8*)(As + (wr * 64 + mi * 16 + lane15) * 32 + quad * 8);
#pragma unroll
        for (int ni = 0; ni < 2; ni++)
            bfr[ni] = *(const bf16x8*)(Bs + (wc * 32 + ni * 16 + lane15) * 32 + quad * 8);
#pragma unroll
        for (int mi = 0; mi < 4; mi++)
#pragma unroll
            for (int ni = 0; ni < 2; ni++)
                acc[mi][ni] = __builtin_amdgcn_mfma_f32_16x16x32_bf16(afr[mi], bfr[ni], acc[mi][ni], 0, 0, 0);
        __syncthreads();
    }

#pragma unroll
    for (int ni = 0; ni < 2; ni++) {
        int col = colBase + wc * 32 + ni * 16 + lane15;
        float bias = bia[col];
#pragma unroll
        for (int mi = 0; mi < 4; mi++) {
#pragma unroll
            for (int r = 0; r < 4; r++) {
                int row = rowBase + wr * 64 + mi * 16 + quad * 4 + r;
                out[(size_t)row * 1024 + col] = acc[mi][ni][r] + bias;
            }
        }
    }
}

// ---------------------------------------------------------------------------
// Flash attention v4: LDS-staged K/V (double-buffered) with 32 q-rows/wave
// and TRANSPOSED scores (S^T = K*Q^T) so P is written packed b64 in A-operand
// order. Row-sums via ones-MFMA. Fixed-max exp2 softmax. Block = 128 q-rows.
// XCD swizzle: blockIdx.x = bh.
// Q,K bf16 [B,H,L,DK]; V bf16 [B,H,DK,L]. attn out [B,L,H,DK].
// ---------------------------------------------------------------------------
#define FS 72   // LDS row stride (bf16): 144 B = 16B-aligned, non-pow2 banks

__global__ __launch_bounds__(256, 2) void flash_kernel(
    const bf16_t* __restrict__ QKV, const int* __restrict__ mask,
    const int* __restrict__ flags, bf16_t* __restrict__ attnout)
{
    __shared__ bf16_t Ks[2][64 * FS];
    __shared__ bf16_t Vs[2][64 * FS];
    __shared__ bf16_t Ps[8 * 16 * FS];      // 4 waves x 2 q-subtiles
    const int t = threadIdx.x, w = t >> 6, lane = t & 63;
    const int lane15 = lane & 15, quad = lane >> 4;
    const int qt = blockIdx.y, bh = blockIdx.x;   // swizzled
    const int b = bh >> 4, h = bh & 15;
    const bf16_t* Q  = QKV;
    const bf16_t* K  = QKV + 4194304;
    const bf16_t* Vt = QKV + 8388608;
    const int qrow0 = qt * 128 + w * 32;

    bf16x8 aq[2][2];
#pragma unroll
    for (int qf = 0; qf < 2; qf++) {
        const bf16_t* qb = Q + ((size_t)bh * 2048 + qrow0 + qf * 16 + lane15) * 64;
        aq[qf][0] = *(const bf16x8*)(qb + quad * 8);
        aq[qf][1] = *(const bf16x8*)(qb + 32 + quad * 8);
#pragma unroll
        for (int j = 0; j < 8; j++) {   // exact: *2^-3
            aq[qf][0][j] = (bf16_t)((float)aq[qf][0][j] * 0.125f);
            aq[qf][1][j] = (bf16_t)((float)aq[qf][1][j] * 0.125f);
        }
    }

    f32x4 zf = {0.f, 0.f, 0.f, 0.f};
    f32x4 o[2][4];
#pragma unroll
    for (int qf = 0; qf < 2; qf++)
#pragma unroll
        for (int df = 0; df < 4; df++) o[qf][df] = zf;
    f32x4 lsum[2] = {zf, zf};
    bf16_t* Pw0 = Ps + (w * 2 + 0) * 16 * FS;
    bf16_t* Pw1 = Ps + (w * 2 + 1) * 16 * FS;
    bf16x8 ones;
#pragma unroll
    for (int j = 0; j < 8; j++) ones[j] = (bf16_t)1.0f;

    const int e0 = t * 8, e1 = (256 + t) * 8;
    const int kr0 = e0 >> 6, kc0 = e0 & 63, kr1 = e1 >> 6, kc1 = e1 & 63;
    const int* flagrow = flags + (b * 32 + qt) * 32;
    const bf16_t* Kb  = K  + (size_t)bh * 131072;
    const bf16_t* Vtb = Vt + (size_t)bh * 131072;

    {
        bf16x8 k0v = *(const bf16x8*)(Kb  + (size_t)kr0 * 64 + kc0);
        bf16x8 k1v = *(const bf16x8*)(Kb  + (size_t)kr1 * 64 + kc1);
        bf16x8 v0v = *(const bf16x8*)(Vtb + (size_t)kr0 * 2048 + kc0);
        bf16x8 v1v = *(const bf16x8*)(Vtb + (size_t)kr1 * 2048 + kc1);
        *(bf16x8*)(Ks[0] + kr0 * FS + kc0) = k0v;
        *(bf16x8*)(Ks[0] + kr1 * FS + kc1) = k1v;
        *(bf16x8*)(Vs[0] + kr0 * FS + kc0) = v0v;
        *(bf16x8*)(Vs[0] + kr1 * FS + kc1) = v1v;
    }
    __syncthreads();

    for (int kt = 0; kt < 32; kt++) {
        const int cur = kt & 1, nxt = cur ^ 1;
        bf16x8 k0v, k1v, v0v, v1v;
        if (kt + 1 < 32) {
            int kn = (kt + 1) * 64;
            k0v = *(const bf16x8*)(Kb  + (size_t)(kn + kr0) * 64 + kc0);
            k1v = *(const bf16x8*)(Kb  + (size_t)(kn + kr1) * 64 + kc1);
            v0v = *(const bf16x8*)(Vtb + (size_t)kr0 * 2048 + kn + kc0);
            v1v = *(const bf16x8*)(Vtb + (size_t)kr1 * 2048 + kn + kc1);
        }

        f32x4 st[2][4];
#pragma unroll
        for (int kf = 0; kf < 4; kf++) {
            bf16x8 kb0 = *(const bf16x8*)(Ks[cur] + (kf * 16 + lane15) * FS + quad * 8);
            bf16x8 kb1 = *(const bf16x8*)(Ks[cur] + (kf * 16 + lane15) * FS + 32 + quad * 8);
#pragma unroll
            for (int qf = 0; qf < 2; qf++) {
                f32x4 a = zf;
                a = __builtin_amdgcn_mfma_f32_16x16x32_bf16(kb0, aq[qf][0], a, 0, 0, 0);
                a = __builtin_amdgcn_mfma_f32_16x16x32_bf16(kb1, aq[qf][1], a, 0, 0, 0);
                st[qf][kf] = a * 1.44269504f;
            }
        }
        if (kt + 1 < 32) {
            *(bf16x8*)(Ks[nxt] + kr0 * FS + kc0) = k0v;
            *(bf16x8*)(Ks[nxt] + kr1 * FS + kc1) = k1v;
            *(bf16x8*)(Vs[nxt] + kr0 * FS + kc0) = v0v;
            *(bf16x8*)(Vs[nxt] + kr1 * FS + kc1) = v1v;
        }
        if (!flagrow[kt]) {
#pragma unroll
            for (int qf = 0; qf < 2; qf++)
#pragma unroll
                for (int kf = 0; kf < 4; kf++)
#pragma unroll
                    for (int r = 0; r < 4; r++) {
                        int qrow = qrow0 + qf * 16 + lane15;
                        int kpos = kt * 64 + kf * 16 + quad * 4 + r;
                        if (mask[((size_t)b * 2048 + qrow) * 2048 + kpos] == 0)
                            st[qf][kf][r] = -1e30f;
                    }
        }
#pragma unroll
        for (int qf = 0; qf < 2; qf++) {
            bf16_t* Pq = qf ? Pw1 : Pw0;
#pragma unroll
            for (int kf = 0; kf < 4; kf++) {
                bf16x4 pv;
#pragma unroll
                for (int r = 0; r < 4; r++) pv[r] = (bf16_t)exp2f(st[qf][kf][r]);
                *(bf16x4*)(Pq + lane15 * FS + kf * 16 + quad * 4) = pv;
            }
        }
        bf16x8 pa[2][2];
        pa[0][0] = *(const bf16x8*)(Pw0 + lane15 * FS + quad * 8);
        pa[0][1] = *(const bf16x8*)(Pw0 + lane15 * FS + 32 + quad * 8);
        pa[1][0] = *(const bf16x8*)(Pw1 + lane15 * FS + quad * 8);
        pa[1][1] = *(const bf16x8*)(Pw1 + lane15 * FS + 32 + quad * 8);
#pragma unroll
        for (int qf = 0; qf < 2; qf++) {
            lsum[qf] = __builtin_amdgcn_mfma_f32_16x16x32_bf16(ones, pa[qf][0], lsum[qf], 0, 0, 0);
            lsum[qf] = __builtin_amdgcn_mfma_f32_16x16x32_bf16(ones, pa[qf][1], lsum[qf], 0, 0, 0);
        }
#pragma unroll
        for (int df = 0; df < 4; df++) {
            bf16x8 vb0 = *(const bf16x8*)(Vs[cur] + (df * 16 + lane15) * FS + quad * 8);
            bf16x8 vb1 = *(const bf16x8*)(Vs[cur] + (df * 16 + lane15) * FS + 32 + quad * 8);
#pragma unroll
            for (int qf = 0; qf < 2; qf++) {
                o[qf][df] = __builtin_amdgcn_mfma_f32_16x16x32_bf16(pa[qf][0], vb0, o[qf][df], 0, 0, 0);
                o[qf][df] = __builtin_amdgcn_mfma_f32_16x16x32_bf16(pa[qf][1], vb1, o[qf][df], 0, 0, 0);
            }
        }
        __syncthreads();
    }

#pragma unroll
    for (int qf = 0; qf < 2; qf++) {
        float lv = lsum[qf][0];
#pragma unroll
        for (int r = 0; r < 4; r++) {
            float inv = 1.0f / __shfl(lv, quad * 4 + r, 64);
            size_t row = (size_t)b * 2048 + qrow0 + qf * 16 + quad * 4 + r;
#pragma unroll
            for (int df = 0; df < 4; df++)
                attnout[(row * 16 + h) * 64 + df * 16 + lane15] = (bf16_t)(o[qf][df][r] * inv);
        }
    }
}

// ---------------------------------------------------------------------------
// Inter-head attention: one wave per position (b,l). attn is [B,L,H,DK].
// ---------------------------------------------------------------------------
__global__ __launch_bounds__(256, 2) void interhead_kernel(
    const bf16_t* __restrict__ attn,
    const bf16_t* __restrict__ whqT, const float* __restrict__ bhq,
    const bf16_t* __restrict__ whkT, const float* __restrict__ bhk,
    const bf16_t* __restrict__ whvT, const float* __restrict__ bhv,
    bf16_t* __restrict__ concat)
{
    __shared__ bf16_t lds[4 * 4608];
    const int t = threadIdx.x, w = t >> 6, lane = t & 63;
    const int lane15 = lane & 15, quad = lane >> 4;
    bf16_t* Qh  = lds + w * 4608;   // [16][64]
    bf16_t* Kh  = Qh + 1024;        // [16][64]
    bf16_t* VhT = Kh + 1024;        // [64][32] (k-padded)
    bf16_t* P16 = VhT + 2048;       // [16][32] (k-padded)
    const int p = blockIdx.x * 4 + w;

    bf16x8 z8 = {(bf16_t)0.f, (bf16_t)0.f, (bf16_t)0.f, (bf16_t)0.f,
                 (bf16_t)0.f, (bf16_t)0.f, (bf16_t)0.f, (bf16_t)0.f};
    ((bf16x8*)P16)[lane] = z8;
#pragma unroll
    for (int i = 0; i < 4; i++) ((bf16x8*)VhT)[i * 64 + lane] = z8;

    const bf16_t* hb = attn + ((size_t)p * 16 + lane15) * 64;
    bf16x8 ha0 = *(const bf16x8*)(hb + quad * 8);
    bf16x8 ha1 = *(const bf16x8*)(hb + 32 + quad * 8);

    const bf16_t* Wt[3] = {whqT, whkT, whvT};
    const float*  Bb[3] = {bhq, bhk, bhv};
    f32x4 zf = {0.f, 0.f, 0.f, 0.f};
#pragma unroll
    for (int m3 = 0; m3 < 3; m3++) {
#pragma unroll
        for (int nf = 0; nf < 4; nf++) {
            f32x4 acc = zf;
            bf16x8 wb0 = *(const bf16x8*)(Wt[m3] + (nf * 16 + lane15) * 64 + quad * 8);
            bf16x8 wb1 = *(const bf16x8*)(Wt[m3] + (nf * 16 + lane15) * 64 + 32 + quad * 8);
            acc = __builtin_amdgcn_mfma_f32_16x16x32_bf16(ha0, wb0, acc, 0, 0, 0);
            acc = __builtin_amdgcn_mfma_f32_16x16x32_bf16(ha1, wb1, acc, 0, 0, 0);
            float bias = Bb[m3][nf * 16 + lane15];
#pragma unroll
            for (int r = 0; r < 4; r++) {
                float v = acc[r] + bias;
                if (m3 == 0) v *= 0.125f;   // fold inter scale into Qh (exact)
                if (m3 == 2) VhT[(nf * 16 + lane15) * 32 + quad * 4 + r] = (bf16_t)v;
                else if (m3 == 0) Qh[(quad * 4 + r) * 64 + nf * 16 + lane15] = (bf16_t)v;
                else Kh[(quad * 4 + r) * 64 + nf * 16 + lane15] = (bf16_t)v;
            }
        }
    }
    __syncthreads();

    bf16x8 qa0 = *(const bf16x8*)(Qh + lane15 * 64 + quad * 8);
    bf16x8 qa1 = *(const bf16x8*)(Qh + lane15 * 64 + 32 + quad * 8);
    bf16x8 kb0 = *(const bf16x8*)(Kh + lane15 * 64 + quad * 8);
    bf16x8 kb1 = *(const bf16x8*)(Kh + lane15 * 64 + 32 + quad * 8);
    f32x4 s = zf;
    s = __builtin_amdgcn_mfma_f32_16x16x32_bf16(qa0, kb0, s, 0, 0, 0);
    s = __builtin_amdgcn_mfma_f32_16x16x32_bf16(qa1, kb1, s, 0, 0, 0);
#pragma unroll
    for (int r = 0; r < 4; r++) {
        float v = s[r];
        float mx = v;
        mx = fmaxf(mx, __shfl_xor(mx, 1));
        mx = fmaxf(mx, __shfl_xor(mx, 2));
        mx = fmaxf(mx, __shfl_xor(mx, 4));
        mx = fmaxf(mx, __shfl_xor(mx, 8));
        float pv = __expf(v - mx);
        float sm = pv;
        sm += __shfl_xor(sm, 1);
        sm += __shfl_xor(sm, 2);
        sm += __shfl_xor(sm, 4);
        sm += __shfl_xor(sm, 8);
        P16[(quad * 4 + r) * 32 + lane15] = (bf16_t)(pv / sm);
    }
    __syncthreads();

    bf16x8 pa = *(const bf16x8*)(P16 + lane15 * 32 + quad * 8);
    bf16_t* outp = concat + (size_t)p * 1024;
#pragma unroll
    for (int df = 0; df < 4; df++) {
        bf16x8 vb = *(const bf16x8*)(VhT + (df * 16 + lane15) * 32 + quad * 8);
        f32x4 mix = zf;
        mix = __builtin_amdgcn_mfma_f32_16x16x32_bf16(pa, vb, mix, 0, 0, 0);
#pragma unroll
        for (int r = 0; r < 4; r++)
            outp[(quad * 4 + r) * 64 + df * 16 + lane15] = (bf16_t)mix[r];
    }
}

// ---------------------------------------------------------------------------
extern "C" void kernel_launch(void* const* d_in, const int* in_sizes, int n_in,
                              void* d_out, int out_size, void* d_ws, size_t ws_size,
                              hipStream_t stream)
{
    const float* q_in = (const float*)d_in[0];
    const float* k_in = (const float*)d_in[1];
    const float* v_in = (const float*)d_in[2];
    const int*   mask = (const int*)d_in[3];
    const float* wq = (const float*)d_in[4];
    const float* bq = (const float*)d_in[5];
    const float* wk = (const float*)d_in[6];
    const float* bk = (const float*)d_in[7];
    const float* wv = (const float*)d_in[8];
    const float* bv = (const float*)d_in[9];
    const float* wo = (const float*)d_in[10];
    const float* bo = (const float*)d_in[11];
    const float* whq = (const float*)d_in[12];
    const float* bhq = (const float*)d_in[13];
    const float* whk = (const float*)d_in[14];
    const float* bhk = (const float*)d_in[15];
    const float* whv = (const float*)d_in[16];
    const float* bhv = (const float*)d_in[17];
    float* out = (float*)d_out;         // [4096][1024] f32 = 16 MB

    char* ws = (char*)d_ws;
    bf16_t* qkvb  = (bf16_t*)ws;                       // 24 MB: Q|K|Vt
    bf16_t* concat = qkvb;                             // Q region, post-flash
    bf16_t* woT   = (bf16_t*)(ws + 8u * 1024 * 1024);  // K region, post-flash
    bf16_t* whqT  = (bf16_t*)(ws + 10u * 1024 * 1024);
    bf16_t* whkT  = whqT + 4096;
    bf16_t* whvT  = whqT + 8192;
    bf16_t* attnb = (bf16_t*)d_out;                    // 8 MB bf16 in d_out
    bf16_t* wqkvT = (bf16_t*)((char*)d_out + 8u * 1024 * 1024);
    int*    flags = (int*)((char*)d_out + 14u * 1024 * 1024);

    maskflags_kernel<<<2048, 256, 0, stream>>>(mask, flags);
    transpose_qkvw_kernel<<<dim3(16, 16, 3), 256, 0, stream>>>(wq, wk, wv, wqkvT);
    gemm_qkv_kernel<<<dim3(32, 8, 3), 256, 0, stream>>>(q_in, k_in, v_in, wqkvT, bq, bk, bv, qkvb);
    flash_kernel<<<dim3(32, 16), 256, 0, stream>>>(qkvb, mask, flags, attnb);
    transpose_one_kernel<<<dim3(16, 16), 256, 0, stream>>>(wo, woT);
    transpose_small_kernel<<<3, 256, 0, stream>>>(whq, whk, whv, whqT, whkT, whvT);
    interhead_kernel<<<1024, 256, 0, stream>>>(attnb, whqT, bhq, whkT, bhk, whvT, bhv, concat);
    gemm_out_kernel<<<dim3(32, 16), 256, 0, stream>>>(concat, woT, bo, out);
    (void)in_sizes; (void)n_in; (void)out_size; (void)ws_size;
}

// Round 12
// 339.057 us; speedup vs baseline: 1.0116x; 1.0116x over previous
//
#include <hip/hip_runtime.h>
#include <hip/hip_bf16.h>

typedef __bf16 bf16_t;
typedef __bf16 bf16x4 __attribute__((ext_vector_type(4)));
typedef __bf16 bf16x8 __attribute__((ext_vector_type(8)));
typedef float f32x4 __attribute__((ext_vector_type(4)));

typedef __attribute__((address_space(1))) unsigned char glob_u8;
typedef __attribute__((address_space(3))) unsigned char lds_u8;

__device__ __forceinline__ void load_lds16(const void* g, void* l) {
    __builtin_amdgcn_global_load_lds((glob_u8*)g, (lds_u8*)l, 16, 0, 0);
}

// ---------------------------------------------------------------------------
// prep1: maskflags (blocks 0..2047) + qkv weight transposes (2048..2815)
// ---------------------------------------------------------------------------
__global__ void prep1_kernel(const int* __restrict__ mask, int* __restrict__ flags,
                             const float* __restrict__ wq, const float* __restrict__ wk,
                             const float* __restrict__ wv, bf16_t* __restrict__ wqkvT)
{
    const int bid = blockIdx.x, t = threadIdx.x;
    if (bid < 2048) {
        int b = bid >> 10, qt = (bid >> 5) & 31, kt = bid & 31;
        int ok = 1;
#pragma unroll
        for (int i = 0; i < 16; i++) {
            int e = t + i * 256; int r = e >> 6, c = e & 63;
            ok &= (mask[((size_t)b * 2048 + qt * 64 + r) * 2048 + kt * 64 + c] != 0) ? 1 : 0;
        }
        ok = __syncthreads_and(ok);
        if (t == 0) flags[bid] = ok;
    } else {
        __shared__ bf16_t tile[64][65];
        int idx = bid - 2048;
        int z = idx >> 8, rem = idx & 255;
        const float* src = (z == 0) ? wq : (z == 1) ? wk : wv;
        bf16_t* dst = wqkvT + (size_t)z * 1048576;
        int rB = (rem >> 4) * 64, cB = (rem & 15) * 64;
#pragma unroll
        for (int i = 0; i < 16; i++) {
            int e = t + i * 256; int r = e >> 6, c = e & 63;
            tile[r][c] = (bf16_t)src[(size_t)(rB + r) * 1024 + cB + c];
        }
        __syncthreads();
#pragma unroll
        for (int i = 0; i < 16; i++) {
            int e = t + i * 256; int r = e >> 6, c = e & 63;
            dst[(size_t)(cB + r) * 1024 + rB + c] = tile[c][r];
        }
    }
}

// ---------------------------------------------------------------------------
// prep2: wo transpose (blocks 0..255) + small inter-head weight transposes
// ---------------------------------------------------------------------------
__global__ void prep2_kernel(const float* __restrict__ wo, bf16_t* __restrict__ woT,
                             const float* __restrict__ s0, const float* __restrict__ s1,
                             const float* __restrict__ s2,
                             bf16_t* __restrict__ d0, bf16_t* __restrict__ d1, bf16_t* __restrict__ d2)
{
    const int bid = blockIdx.x, t = threadIdx.x;
    if (bid < 256) {
        __shared__ bf16_t tile[64][65];
        int rB = (bid >> 4) * 64, cB = (bid & 15) * 64;
#pragma unroll
        for (int i = 0; i < 16; i++) {
            int e = t + i * 256; int r = e >> 6, c = e & 63;
            tile[r][c] = (bf16_t)wo[(size_t)(rB + r) * 1024 + cB + c];
        }
        __syncthreads();
#pragma unroll
        for (int i = 0; i < 16; i++) {
            int e = t + i * 256; int r = e >> 6, c = e & 63;
            woT[(size_t)(cB + r) * 1024 + rB + c] = tile[c][r];
        }
    } else {
        int z = bid - 256;
        const float* src = (z == 0) ? s0 : (z == 1) ? s1 : s2;
        bf16_t* dst = (z == 0) ? d0 : (z == 1) ? d1 : d2;
#pragma unroll
        for (int i = 0; i < 16; i++) {
            int e = t + i * 256; int r = e >> 6, c = e & 63;
            dst[c * 64 + r] = (bf16_t)src[r * 64 + c];
        }
    }
}

// ---------------------------------------------------------------------------
// QKV GEMM (round-8 proven config, 73 us): A f32, Bt (weights^T) bf16.
// 128x128 C-tile, BK=32, explicit staging, GS=40 padded LDS.
// XCD swizzle: blockIdx.x = row tile. z<2: C -> [B,H,L,DK].
// z==2: transposed accumulate (C^T) so [B,H,DK,L] store is coalesced.
// ---------------------------------------------------------------------------
#define GS 40   // GEMM LDS row stride (bf16 elems) for a 32-wide K tile

__global__ __launch_bounds__(256, 2) void gemm_qkv_kernel(
    const float* __restrict__ Aq, const float* __restrict__ Ak, const float* __restrict__ Av,
    const bf16_t* __restrict__ WT,
    const float* __restrict__ bq, const float* __restrict__ bk, const float* __restrict__ bv,
    bf16_t* __restrict__ outbase)
{
    __shared__ bf16_t As[128 * GS];
    __shared__ bf16_t Bs[128 * GS];
    const int z = blockIdx.z;
    const float* A    = (z == 0) ? Aq : (z == 1) ? Ak : Av;
    const bf16_t* Bt  = WT + (size_t)z * 1048576;
    const float* bia  = (z == 0) ? bq : (z == 1) ? bk : bv;
    bf16_t* out = outbase + (size_t)z * 4194304;

    const int t = threadIdx.x;
    const int w = t >> 6, lane = t & 63;
    const int lane15 = lane & 15, quad = lane >> 4;
    const int wr = w >> 1, wc = w & 1;
    const int rowBase = blockIdx.x * 128, colBase = blockIdx.y * 128;

    const int ar = t >> 1, ac = (t & 1) * 16;
    const int e0 = t * 8, e1 = (256 + t) * 8;
    const int r0 = e0 >> 5, c0 = e0 & 31;
    const int r1 = e1 >> 5, c1 = e1 & 31;

    f32x4 acc[4][4];
    f32x4 zf = {0.f, 0.f, 0.f, 0.f};
#pragma unroll
    for (int i = 0; i < 4; i++)
#pragma unroll
        for (int j = 0; j < 4; j++) acc[i][j] = zf;

    for (int k0 = 0; k0 < 1024; k0 += 32) {
        const float4* ap = (const float4*)(A + (size_t)(rowBase + ar) * 1024 + k0 + ac);
        float4 af4[4];
#pragma unroll
        for (int i = 0; i < 4; i++) af4[i] = ap[i];
        bf16x8 b0 = *(const bf16x8*)(Bt + (size_t)(colBase + r0) * 1024 + k0 + c0);
        bf16x8 b1 = *(const bf16x8*)(Bt + (size_t)(colBase + r1) * 1024 + k0 + c1);
        bf16x8 av0, av1;
#pragma unroll
        for (int i = 0; i < 4; i++) {
            bf16x8& dstv = (i < 2) ? av0 : av1;
            int base = (i & 1) * 4;
            dstv[base + 0] = (bf16_t)af4[i].x; dstv[base + 1] = (bf16_t)af4[i].y;
            dstv[base + 2] = (bf16_t)af4[i].z; dstv[base + 3] = (bf16_t)af4[i].w;
        }
        *(bf16x8*)(As + ar * GS + ac) = av0;
        *(bf16x8*)(As + ar * GS + ac + 8) = av1;
        *(bf16x8*)(Bs + r0 * GS + c0) = b0;
        *(bf16x8*)(Bs + r1 * GS + c1) = b1;
        __syncthreads();
        bf16x8 afr[4], bfr[4];
#pragma unroll
        for (int mi = 0; mi < 4; mi++)
            afr[mi] = *(const bf16x8*)(As + (wr * 64 + mi * 16 + lane15) * GS + quad * 8);
#pragma unroll
        for (int ni = 0; ni < 4; ni++)
            bfr[ni] = *(const bf16x8*)(Bs + (wc * 64 + ni * 16 + lane15) * GS + quad * 8);
        if (z < 2) {
#pragma unroll
            for (int mi = 0; mi < 4; mi++)
#pragma unroll
                for (int ni = 0; ni < 4; ni++)
                    acc[mi][ni] = __builtin_amdgcn_mfma_f32_16x16x32_bf16(afr[mi], bfr[ni], acc[mi][ni], 0, 0, 0);
        } else {    // transposed accumulation for coalesced Vt store
#pragma unroll
            for (int mi = 0; mi < 4; mi++)
#pragma unroll
                for (int ni = 0; ni < 4; ni++)
                    acc[mi][ni] = __builtin_amdgcn_mfma_f32_16x16x32_bf16(bfr[ni], afr[mi], acc[mi][ni], 0, 0, 0);
        }
        __syncthreads();
    }

    if (z < 2) {
        // C[row=l][col=dout], col = lane15 -> [B,H,L,DK]
#pragma unroll
        for (int ni = 0; ni < 4; ni++) {
            int col = colBase + wc * 64 + ni * 16 + lane15;   // dout
            float bias = bia[col];
            int h = col >> 6, dk = col & 63;
#pragma unroll
            for (int mi = 0; mi < 4; mi++) {
#pragma unroll
                for (int r = 0; r < 4; r++) {
                    int row = rowBase + wr * 64 + mi * 16 + quad * 4 + r;
                    int b = row >> 11, l = row & 2047;
                    out[((((size_t)(b * 16 + h)) * 2048 + l) * 64 + dk)] =
                        (bf16_t)(acc[mi][ni][r] + bias);
                }
            }
        }
    } else {
        // C^T[row=dout][col=l], col = lane15 -> coalesced [B,H,DK,L]
#pragma unroll
        for (int ni = 0; ni < 4; ni++) {
#pragma unroll
            for (int r = 0; r < 4; r++) {
                int dout = colBase + wc * 64 + ni * 16 + quad * 4 + r;
                float bias = bia[dout];
                int h = dout >> 6, dk = dout & 63;
#pragma unroll
                for (int mi = 0; mi < 4; mi++) {
                    int rowl = rowBase + wr * 64 + mi * 16 + lane15;
                    int b = rowl >> 11, l = rowl & 2047;
                    out[((((size_t)(b * 16 + h)) * 64 + dk) * 2048 + l)] =
                        (bf16_t)(acc[mi][ni][r] + bias);
                }
            }
        }
    }
}

// ---------------------------------------------------------------------------
// Output projection: A (concat) bf16, Bt (woT) bf16, out f32.
// 128x64 tile -> 512 blocks. m97 DMA staging, unpadded layout.
// ---------------------------------------------------------------------------
__global__ __launch_bounds__(256, 2) void gemm_out_kernel(
    const bf16_t* __restrict__ A, const bf16_t* __restrict__ Bt,
    const float* __restrict__ bia, float* __restrict__ out)
{
    __shared__ bf16_t As[128 * 32];     // 8 KB
    __shared__ bf16_t Bs[64 * 32];      // 4 KB
    const int t = threadIdx.x;
    const int w = t >> 6, lane = t & 63;
    const int lane15 = lane & 15, quad = lane >> 4;
    const int wr = w >> 1, wc = w & 1;
    const int rowBase = blockIdx.x * 128, colBase = blockIdx.y * 64;

    const int brow = lane >> 2, bcol = (lane & 3) * 8;  // bf16 chunk map

    f32x4 acc[4][2];
    f32x4 zf = {0.f, 0.f, 0.f, 0.f};
#pragma unroll
    for (int i = 0; i < 4; i++)
#pragma unroll
        for (int j = 0; j < 2; j++) acc[i][j] = zf;

    for (int k0 = 0; k0 < 1024; k0 += 32) {
#pragma unroll
        for (int j = 0; j < 2; j++) {   // 2 A-chunks per wave
            int chunk = w * 2 + j;
            load_lds16(A + (size_t)(rowBase + chunk * 16 + brow) * 1024 + k0 + bcol,
                       (char*)As + chunk * 1024);
        }
        {                               // 1 B-chunk per wave
            int chunk = w;
            load_lds16(Bt + (size_t)(colBase + chunk * 16 + brow) * 1024 + k0 + bcol,
                       (char*)Bs + chunk * 1024);
        }
        __syncthreads();
        bf16x8 afr[4], bfr[2];
#pragma unroll
        for (int mi = 0; mi < 4; mi++)
            afr[mi] = *(const bf16x8*)(As + (wr * 64 + mi * 16 + lane15) * 32 + quad * 8);
#pragma unroll
        for (int ni = 0; ni < 2; ni++)
            bfr[ni] = *(const bf16x8*)(Bs + (wc * 32 + ni * 16 + lane15) * 32 + quad * 8);
#pragma unroll
        for (int mi = 0; mi < 4; mi++)
#pragma unroll
            for (int ni = 0; ni < 2; ni++)
                acc[mi][ni] = __builtin_amdgcn_mfma_f32_16x16x32_bf16(afr[mi], bfr[ni], acc[mi][ni], 0, 0, 0);
        __syncthreads();
    }

#pragma unroll
    for (int ni = 0; ni < 2; ni++) {
        int col = colBase + wc * 32 + ni * 16 + lane15;
        float bias = bia[col];
#pragma unroll
        for (int mi = 0; mi < 4; mi++) {
#pragma unroll
            for (int r = 0; r < 4; r++) {
                int row = rowBase + wr * 64 + mi * 16 + quad * 4 + r;
                out[(size_t)row * 1024 + col] = acc[mi][ni][r] + bias;
            }
        }
    }
}

// ---------------------------------------------------------------------------
// Flash attention v4: LDS-staged K/V (double-buffered) with 32 q-rows/wave
// and TRANSPOSED scores (S^T = K*Q^T) so P is written packed b64 in A-operand
// order. Row-sums via ones-MFMA. Fixed-max exp2 softmax. Block = 128 q-rows.
// XCD swizzle: blockIdx.x = bh.
// Q,K bf16 [B,H,L,DK]; V bf16 [B,H,DK,L]. attn out [B,L,H,DK].
// ---------------------------------------------------------------------------
#define FS 72   // LDS row stride (bf16): 144 B = 16B-aligned, non-pow2 banks

__global__ __launch_bounds__(256, 2) void flash_kernel(
    const bf16_t* __restrict__ QKV, const int* __restrict__ mask,
    const int* __restrict__ flags, bf16_t* __restrict__ attnout)
{
    __shared__ bf16_t Ks[2][64 * FS];
    __shared__ bf16_t Vs[2][64 * FS];
    __shared__ bf16_t Ps[8 * 16 * FS];      // 4 waves x 2 q-subtiles
    const int t = threadIdx.x, w = t >> 6, lane = t & 63;
    const int lane15 = lane & 15, quad = lane >> 4;
    const int qt = blockIdx.y, bh = blockIdx.x;   // swizzled
    const int b = bh >> 4, h = bh & 15;
    const bf16_t* Q  = QKV;
    const bf16_t* K  = QKV + 4194304;
    const bf16_t* Vt = QKV + 8388608;
    const int qrow0 = qt * 128 + w * 32;

    bf16x8 aq[2][2];
#pragma unroll
    for (int qf = 0; qf < 2; qf++) {
        const bf16_t* qb = Q + ((size_t)bh * 2048 + qrow0 + qf * 16 + lane15) * 64;
        aq[qf][0] = *(const bf16x8*)(qb + quad * 8);
        aq[qf][1] = *(const bf16x8*)(qb + 32 + quad * 8);
#pragma unroll
        for (int j = 0; j < 8; j++) {   // exact: *2^-3
            aq[qf][0][j] = (bf16_t)((float)aq[qf][0][j] * 0.125f);
            aq[qf][1][j] = (bf16_t)((float)aq[qf][1][j] * 0.125f);
        }
    }

    f32x4 zf = {0.f, 0.f, 0.f, 0.f};
    f32x4 o[2][4];
#pragma unroll
    for (int qf = 0; qf < 2; qf++)
#pragma unroll
        for (int df = 0; df < 4; df++) o[qf][df] = zf;
    f32x4 lsum[2] = {zf, zf};
    bf16_t* Pw0 = Ps + (w * 2 + 0) * 16 * FS;
    bf16_t* Pw1 = Ps + (w * 2 + 1) * 16 * FS;
    bf16x8 ones;
#pragma unroll
    for (int j = 0; j < 8; j++) ones[j] = (bf16_t)1.0f;

    const int e0 = t * 8, e1 = (256 + t) * 8;
    const int kr0 = e0 >> 6, kc0 = e0 & 63, kr1 = e1 >> 6, kc1 = e1 & 63;
    const int* flagrow = flags + (b * 32 + qt) * 32;
    const bf16_t* Kb  = K  + (size_t)bh * 131072;
    const bf16_t* Vtb = Vt + (size_t)bh * 131072;

    {
        bf16x8 k0v = *(const bf16x8*)(Kb  + (size_t)kr0 * 64 + kc0);
        bf16x8 k1v = *(const bf16x8*)(Kb  + (size_t)kr1 * 64 + kc1);
        bf16x8 v0v = *(const bf16x8*)(Vtb + (size_t)kr0 * 2048 + kc0);
        bf16x8 v1v = *(const bf16x8*)(Vtb + (size_t)kr1 * 2048 + kc1);
        *(bf16x8*)(Ks[0] + kr0 * FS + kc0) = k0v;
        *(bf16x8*)(Ks[0] + kr1 * FS + kc1) = k1v;
        *(bf16x8*)(Vs[0] + kr0 * FS + kc0) = v0v;
        *(bf16x8*)(Vs[0] + kr1 * FS + kc1) = v1v;
    }
    __syncthreads();

    for (int kt = 0; kt < 32; kt++) {
        const int cur = kt & 1, nxt = cur ^ 1;
        bf16x8 k0v, k1v, v0v, v1v;
        if (kt + 1 < 32) {
            int kn = (kt + 1) * 64;
            k0v = *(const bf16x8*)(Kb  + (size_t)(kn + kr0) * 64 + kc0);
            k1v = *(const bf16x8*)(Kb  + (size_t)(kn + kr1) * 64 + kc1);
            v0v = *(const bf16x8*)(Vtb + (size_t)kr0 * 2048 + kn + kc0);
            v1v = *(const bf16x8*)(Vtb + (size_t)kr1 * 2048 + kn + kc1);
        }

        f32x4 st[2][4];
#pragma unroll
        for (int kf = 0; kf < 4; kf++) {
            bf16x8 kb0 = *(const bf16x8*)(Ks[cur] + (kf * 16 + lane15) * FS + quad * 8);
            bf16x8 kb1 = *(const bf16x8*)(Ks[cur] + (kf * 16 + lane15) * FS + 32 + quad * 8);
#pragma unroll
            for (int qf = 0; qf < 2; qf++) {
                f32x4 a = zf;
                a = __builtin_amdgcn_mfma_f32_16x16x32_bf16(kb0, aq[qf][0], a, 0, 0, 0);
                a = __builtin_amdgcn_mfma_f32_16x16x32_bf16(kb1, aq[qf][1], a, 0, 0, 0);
                st[qf][kf] = a * 1.44269504f;
            }
        }
        if (kt + 1 < 32) {
            *(bf16x8*)(Ks[nxt] + kr0 * FS + kc0) = k0v;
            *(bf16x8*)(Ks[nxt] + kr1 * FS + kc1) = k1v;
            *(bf16x8*)(Vs[nxt] + kr0 * FS + kc0) = v0v;
            *(bf16x8*)(Vs[nxt] + kr1 * FS + kc1) = v1v;
        }
        if (!flagrow[kt]) {
#pragma unroll
            for (int qf = 0; qf < 2; qf++)
#pragma unroll
                for (int kf = 0; kf < 4; kf++)
#pragma unroll
                    for (int r = 0; r < 4; r++) {
                        int qrow = qrow0 + qf * 16 + lane15;
                        int kpos = kt * 64 + kf * 16 + quad * 4 + r;
                        if (mask[((size_t)b * 2048 + qrow) * 2048 + kpos] == 0)
                            st[qf][kf][r] = -1e30f;
                    }
        }
#pragma unroll
        for (int qf = 0; qf < 2; qf++) {
            bf16_t* Pq = qf ? Pw1 : Pw0;
#pragma unroll
            for (int kf = 0; kf < 4; kf++) {
                bf16x4 pv;
#pragma unroll
                for (int r = 0; r < 4; r++) pv[r] = (bf16_t)exp2f(st[qf][kf][r]);
                *(bf16x4*)(Pq + lane15 * FS + kf * 16 + quad * 4) = pv;
            }
        }
        bf16x8 pa[2][2];
        pa[0][0] = *(const bf16x8*)(Pw0 + lane15 * FS + quad * 8);
        pa[0][1] = *(const bf16x8*)(Pw0 + lane15 * FS + 32 + quad * 8);
        pa[1][0] = *(const bf16x8*)(Pw1 + lane15 * FS + quad * 8);
        pa[1][1] = *(const bf16x8*)(Pw1 + lane15 * FS + 32 + quad * 8);
#pragma unroll
        for (int qf = 0; qf < 2; qf++) {
            lsum[qf] = __builtin_amdgcn_mfma_f32_16x16x32_bf16(ones, pa[qf][0], lsum[qf], 0, 0, 0);
            lsum[qf] = __builtin_amdgcn_mfma_f32_16x16x32_bf16(ones, pa[qf][1], lsum[qf], 0, 0, 0);
        }
#pragma unroll
        for (int df = 0; df < 4; df++) {
            bf16x8 vb0 = *(const bf16x8*)(Vs[cur] + (df * 16 + lane15) * FS + quad * 8);
            bf16x8 vb1 = *(const bf16x8*)(Vs[cur] + (df * 16 + lane15) * FS + 32 + quad * 8);
#pragma unroll
            for (int qf = 0; qf < 2; qf++) {
                o[qf][df] = __builtin_amdgcn_mfma_f32_16x16x32_bf16(pa[qf][0], vb0, o[qf][df], 0, 0, 0);
                o[qf][df] = __builtin_amdgcn_mfma_f32_16x16x32_bf16(pa[qf][1], vb1, o[qf][df], 0, 0, 0);
            }
        }
        __syncthreads();
    }

#pragma unroll
    for (int qf = 0; qf < 2; qf++) {
        float lv = lsum[qf][0];
#pragma unroll
        for (int r = 0; r < 4; r++) {
            float inv = 1.0f / __shfl(lv, quad * 4 + r, 64);
            size_t row = (size_t)b * 2048 + qrow0 + qf * 16 + quad * 4 + r;
#pragma unroll
            for (int df = 0; df < 4; df++)
                attnout[(row * 16 + h) * 64 + df * 16 + lane15] = (bf16_t)(o[qf][df][r] * inv);
        }
    }
}

// ---------------------------------------------------------------------------
// Inter-head attention: one wave per position (b,l). attn is [B,L,H,DK].
// ---------------------------------------------------------------------------
__global__ __launch_bounds__(256, 2) void interhead_kernel(
    const bf16_t* __restrict__ attn,
    const bf16_t* __restrict__ whqT, const float* __restrict__ bhq,
    const bf16_t* __restrict__ whkT, const float* __restrict__ bhk,
    const bf16_t* __restrict__ whvT, const float* __restrict__ bhv,
    bf16_t* __restrict__ concat)
{
    __shared__ bf16_t lds[4 * 4608];
    const int t = threadIdx.x, w = t >> 6, lane = t & 63;
    const int lane15 = lane & 15, quad = lane >> 4;
    bf16_t* Qh  = lds + w * 4608;   // [16][64]
    bf16_t* Kh  = Qh + 1024;        // [16][64]
    bf16_t* VhT = Kh + 1024;        // [64][32] (k-padded)
    bf16_t* P16 = VhT + 2048;       // [16][32] (k-padded)
    const int p = blockIdx.x * 4 + w;

    bf16x8 z8 = {(bf16_t)0.f, (bf16_t)0.f, (bf16_t)0.f, (bf16_t)0.f,
                 (bf16_t)0.f, (bf16_t)0.f, (bf16_t)0.f, (bf16_t)0.f};
    ((bf16x8*)P16)[lane] = z8;
#pragma unroll
    for (int i = 0; i < 4; i++) ((bf16x8*)VhT)[i * 64 + lane] = z8;

    const bf16_t* hb = attn + ((size_t)p * 16 + lane15) * 64;
    bf16x8 ha0 = *(const bf16x8*)(hb + quad * 8);
    bf16x8 ha1 = *(const bf16x8*)(hb + 32 + quad * 8);

    const bf16_t* Wt[3] = {whqT, whkT, whvT};
    const float*  Bb[3] = {bhq, bhk, bhv};
    f32x4 zf = {0.f, 0.f, 0.f, 0.f};
#pragma unroll
    for (int m3 = 0; m3 < 3; m3++) {
#pragma unroll
        for (int nf = 0; nf < 4; nf++) {
            f32x4 acc = zf;
            bf16x8 wb0 = *(const bf16x8*)(Wt[m3] + (nf * 16 + lane15) * 64 + quad * 8);
            bf16x8 wb1 = *(const bf16x8*)(Wt[m3] + (nf * 16 + lane15) * 64 + 32 + quad * 8);
            acc = __builtin_amdgcn_mfma_f32_16x16x32_bf16(ha0, wb0, acc, 0, 0, 0);
            acc = __builtin_amdgcn_mfma_f32_16x16x32_bf16(ha1, wb1, acc, 0, 0, 0);
            float bias = Bb[m3][nf * 16 + lane15];
#pragma unroll
            for (int r = 0; r < 4; r++) {
                float v = acc[r] + bias;
                if (m3 == 0) v *= 0.125f;   // fold inter scale into Qh (exact)
                if (m3 == 2) VhT[(nf * 16 + lane15) * 32 + quad * 4 + r] = (bf16_t)v;
                else if (m3 == 0) Qh[(quad * 4 + r) * 64 + nf * 16 + lane15] = (bf16_t)v;
                else Kh[(quad * 4 + r) * 64 + nf * 16 + lane15] = (bf16_t)v;
            }
        }
    }
    __syncthreads();

    bf16x8 qa0 = *(const bf16x8*)(Qh + lane15 * 64 + quad * 8);
    bf16x8 qa1 = *(const bf16x8*)(Qh + lane15 * 64 + 32 + quad * 8);
    bf16x8 kb0 = *(const bf16x8*)(Kh + lane15 * 64 + quad * 8);
    bf16x8 kb1 = *(const bf16x8*)(Kh + lane15 * 64 + 32 + quad * 8);
    f32x4 s = zf;
    s = __builtin_amdgcn_mfma_f32_16x16x32_bf16(qa0, kb0, s, 0, 0, 0);
    s = __builtin_amdgcn_mfma_f32_16x16x32_bf16(qa1, kb1, s, 0, 0, 0);
#pragma unroll
    for (int r = 0; r < 4; r++) {
        float v = s[r];
        float mx = v;
        mx = fmaxf(mx, __shfl_xor(mx, 1));
        mx = fmaxf(mx, __shfl_xor(mx, 2));
        mx = fmaxf(mx, __shfl_xor(mx, 4));
        mx = fmaxf(mx, __shfl_xor(mx, 8));
        float pv = __expf(v - mx);
        float sm = pv;
        sm += __shfl_xor(sm, 1);
        sm += __shfl_xor(sm, 2);
        sm += __shfl_xor(sm, 4);
        sm += __shfl_xor(sm, 8);
        P16[(quad * 4 + r) * 32 + lane15] = (bf16_t)(pv / sm);
    }
    __syncthreads();

    bf16x8 pa = *(const bf16x8*)(P16 + lane15 * 32 + quad * 8);
    bf16_t* outp = concat + (size_t)p * 1024;
#pragma unroll
    for (int df = 0; df < 4; df++) {
        bf16x8 vb = *(const bf16x8*)(VhT + (df * 16 + lane15) * 32 + quad * 8);
        f32x4 mix = zf;
        mix = __builtin_amdgcn_mfma_f32_16x16x32_bf16(pa, vb, mix, 0, 0, 0);
#pragma unroll
        for (int r = 0; r < 4; r++)
            outp[(quad * 4 + r) * 64 + df * 16 + lane15] = (bf16_t)mix[r];
    }
}

// ---------------------------------------------------------------------------
extern "C" void kernel_launch(void* const* d_in, const int* in_sizes, int n_in,
                              void* d_out, int out_size, void* d_ws, size_t ws_size,
                              hipStream_t stream)
{
    const float* q_in = (const float*)d_in[0];
    const float* k_in = (const float*)d_in[1];
    const float* v_in = (const float*)d_in[2];
    const int*   mask = (const int*)d_in[3];
    const float* wq = (const float*)d_in[4];
    const float* bq = (const float*)d_in[5];
    const float* wk = (const float*)d_in[6];
    const float* bk = (const float*)d_in[7];
    const float* wv = (const float*)d_in[8];
    const float* bv = (const float*)d_in[9];
    const float* wo = (const float*)d_in[10];
    const float* bo = (const float*)d_in[11];
    const float* whq = (const float*)d_in[12];
    const float* bhq = (const float*)d_in[13];
    const float* whk = (const float*)d_in[14];
    const float* bhk = (const float*)d_in[15];
    const float* whv = (const float*)d_in[16];
    const float* bhv = (const float*)d_in[17];
    float* out = (float*)d_out;         // [4096][1024] f32 = 16 MB

    char* ws = (char*)d_ws;
    bf16_t* qkvb  = (bf16_t*)ws;                       // 24 MB: Q|K|Vt
    bf16_t* concat = qkvb;                             // Q region, post-flash
    bf16_t* woT   = (bf16_t*)(ws + 8u * 1024 * 1024);  // K region, post-flash
    bf16_t* whqT  = (bf16_t*)(ws + 10u * 1024 * 1024);
    bf16_t* whkT  = whqT + 4096;
    bf16_t* whvT  = whqT + 8192;
    bf16_t* attnb = (bf16_t*)d_out;                    // 8 MB bf16 in d_out
    bf16_t* wqkvT = (bf16_t*)((char*)d_out + 8u * 1024 * 1024);
    int*    flags = (int*)((char*)d_out + 14u * 1024 * 1024);

    prep1_kernel<<<2816, 256, 0, stream>>>(mask, flags, wq, wk, wv, wqkvT);
    gemm_qkv_kernel<<<dim3(32, 8, 3), 256, 0, stream>>>(q_in, k_in, v_in, wqkvT, bq, bk, bv, qkvb);
    flash_kernel<<<dim3(32, 16), 256, 0, stream>>>(qkvb, mask, flags, attnb);
    prep2_kernel<<<259, 256, 0, stream>>>(wo, woT, whq, whk, whv, whqT, whkT, whvT);
    interhead_kernel<<<1024, 256, 0, stream>>>(attnb, whqT, bhq, whkT, bhk, whvT, bhv, concat);
    gemm_out_kernel<<<dim3(32, 16), 256, 0, stream>>>(concat, woT, bo, out);
    (void)in_sizes; (void)n_in; (void)out_size; (void)ws_size;
}

// Round 13
// 311.920 us; speedup vs baseline: 1.0996x; 1.0870x over previous
//
#include <hip/hip_runtime.h>
#include <hip/hip_bf16.h>

typedef __bf16 bf16_t;
typedef __bf16 bf16x4 __attribute__((ext_vector_type(4)));
typedef __bf16 bf16x8 __attribute__((ext_vector_type(8)));
typedef float f32x4 __attribute__((ext_vector_type(4)));

typedef __attribute__((address_space(1))) unsigned char glob_u8;
typedef __attribute__((address_space(3))) unsigned char lds_u8;

__device__ __forceinline__ void load_lds16(const void* g, void* l) {
    __builtin_amdgcn_global_load_lds((glob_u8*)g, (lds_u8*)l, 16, 0, 0);
}

// ---------------------------------------------------------------------------
// prep1: maskflags (blocks 0..2047) + qkv weight transposes (2048..2815)
// ---------------------------------------------------------------------------
__global__ void prep1_kernel(const int* __restrict__ mask, int* __restrict__ flags,
                             const float* __restrict__ wq, const float* __restrict__ wk,
                             const float* __restrict__ wv, bf16_t* __restrict__ wqkvT)
{
    const int bid = blockIdx.x, t = threadIdx.x;
    if (bid < 2048) {
        int b = bid >> 10, qt = (bid >> 5) & 31, kt = bid & 31;
        int ok = 1;
#pragma unroll
        for (int i = 0; i < 16; i++) {
            int e = t + i * 256; int r = e >> 6, c = e & 63;
            ok &= (mask[((size_t)b * 2048 + qt * 64 + r) * 2048 + kt * 64 + c] != 0) ? 1 : 0;
        }
        ok = __syncthreads_and(ok);
        if (t == 0) flags[bid] = ok;
    } else {
        __shared__ bf16_t tile[64][65];
        int idx = bid - 2048;
        int z = idx >> 8, rem = idx & 255;
        const float* src = (z == 0) ? wq : (z == 1) ? wk : wv;
        bf16_t* dst = wqkvT + (size_t)z * 1048576;
        int rB = (rem >> 4) * 64, cB = (rem & 15) * 64;
#pragma unroll
        for (int i = 0; i < 16; i++) {
            int e = t + i * 256; int r = e >> 6, c = e & 63;
            tile[r][c] = (bf16_t)src[(size_t)(rB + r) * 1024 + cB + c];
        }
        __syncthreads();
#pragma unroll
        for (int i = 0; i < 16; i++) {
            int e = t + i * 256; int r = e >> 6, c = e & 63;
            dst[(size_t)(cB + r) * 1024 + rB + c] = tile[c][r];
        }
    }
}

// ---------------------------------------------------------------------------
// prep2: wo transpose (blocks 0..255) + small inter-head weight transposes
// ---------------------------------------------------------------------------
__global__ void prep2_kernel(const float* __restrict__ wo, bf16_t* __restrict__ woT,
                             const float* __restrict__ s0, const float* __restrict__ s1,
                             const float* __restrict__ s2,
                             bf16_t* __restrict__ d0, bf16_t* __restrict__ d1, bf16_t* __restrict__ d2)
{
    const int bid = blockIdx.x, t = threadIdx.x;
    if (bid < 256) {
        __shared__ bf16_t tile[64][65];
        int rB = (bid >> 4) * 64, cB = (bid & 15) * 64;
#pragma unroll
        for (int i = 0; i < 16; i++) {
            int e = t + i * 256; int r = e >> 6, c = e & 63;
            tile[r][c] = (bf16_t)wo[(size_t)(rB + r) * 1024 + cB + c];
        }
        __syncthreads();
#pragma unroll
        for (int i = 0; i < 16; i++) {
            int e = t + i * 256; int r = e >> 6, c = e & 63;
            woT[(size_t)(cB + r) * 1024 + rB + c] = tile[c][r];
        }
    } else {
        int z = bid - 256;
        const float* src = (z == 0) ? s0 : (z == 1) ? s1 : s2;
        bf16_t* dst = (z == 0) ? d0 : (z == 1) ? d1 : d2;
#pragma unroll
        for (int i = 0; i < 16; i++) {
            int e = t + i * 256; int r = e >> 6, c = e & 63;
            dst[c * 64 + r] = (bf16_t)src[r * 64 + c];
        }
    }
}

// ---------------------------------------------------------------------------
// QKV GEMM (round-8 exact, 73 us): A f32, Bt (weights^T) bf16.
// 128x128 C-tile, BK=32, explicit staging, GS=40 padded LDS. Branchless
// MFMA order (the z-conditional only touches the epilogue address calc).
// XCD swizzle: blockIdx.x = row tile.
// ---------------------------------------------------------------------------
#define GS 40   // GEMM LDS row stride (bf16 elems) for a 32-wide K tile

__global__ __launch_bounds__(256, 2) void gemm_qkv_kernel(
    const float* __restrict__ Aq, const float* __restrict__ Ak, const float* __restrict__ Av,
    const bf16_t* __restrict__ WT,
    const float* __restrict__ bq, const float* __restrict__ bk, const float* __restrict__ bv,
    bf16_t* __restrict__ outbase)
{
    __shared__ bf16_t As[128 * GS];
    __shared__ bf16_t Bs[128 * GS];
    const int z = blockIdx.z;
    const float* A    = (z == 0) ? Aq : (z == 1) ? Ak : Av;
    const bf16_t* Bt  = WT + (size_t)z * 1048576;
    const float* bia  = (z == 0) ? bq : (z == 1) ? bk : bv;
    bf16_t* out = outbase + (size_t)z * 4194304;

    const int t = threadIdx.x;
    const int w = t >> 6, lane = t & 63;
    const int lane15 = lane & 15, quad = lane >> 4;
    const int wr = w >> 1, wc = w & 1;
    const int rowBase = blockIdx.x * 128, colBase = blockIdx.y * 128;

    const int ar = t >> 1, ac = (t & 1) * 16;
    const int e0 = t * 8, e1 = (256 + t) * 8;
    const int r0 = e0 >> 5, c0 = e0 & 31;
    const int r1 = e1 >> 5, c1 = e1 & 31;

    f32x4 acc[4][4];
    f32x4 zf = {0.f, 0.f, 0.f, 0.f};
#pragma unroll
    for (int i = 0; i < 4; i++)
#pragma unroll
        for (int j = 0; j < 4; j++) acc[i][j] = zf;

    for (int k0 = 0; k0 < 1024; k0 += 32) {
        const float4* ap = (const float4*)(A + (size_t)(rowBase + ar) * 1024 + k0 + ac);
        float4 af4[4];
#pragma unroll
        for (int i = 0; i < 4; i++) af4[i] = ap[i];
        bf16x8 b0 = *(const bf16x8*)(Bt + (size_t)(colBase + r0) * 1024 + k0 + c0);
        bf16x8 b1 = *(const bf16x8*)(Bt + (size_t)(colBase + r1) * 1024 + k0 + c1);
        bf16x8 av0, av1;
#pragma unroll
        for (int i = 0; i < 4; i++) {
            bf16x8& dstv = (i < 2) ? av0 : av1;
            int base = (i & 1) * 4;
            dstv[base + 0] = (bf16_t)af4[i].x; dstv[base + 1] = (bf16_t)af4[i].y;
            dstv[base + 2] = (bf16_t)af4[i].z; dstv[base + 3] = (bf16_t)af4[i].w;
        }
        *(bf16x8*)(As + ar * GS + ac) = av0;
        *(bf16x8*)(As + ar * GS + ac + 8) = av1;
        *(bf16x8*)(Bs + r0 * GS + c0) = b0;
        *(bf16x8*)(Bs + r1 * GS + c1) = b1;
        __syncthreads();
        bf16x8 afr[4], bfr[4];
#pragma unroll
        for (int mi = 0; mi < 4; mi++)
            afr[mi] = *(const bf16x8*)(As + (wr * 64 + mi * 16 + lane15) * GS + quad * 8);
#pragma unroll
        for (int ni = 0; ni < 4; ni++)
            bfr[ni] = *(const bf16x8*)(Bs + (wc * 64 + ni * 16 + lane15) * GS + quad * 8);
#pragma unroll
        for (int mi = 0; mi < 4; mi++)
#pragma unroll
            for (int ni = 0; ni < 4; ni++)
                acc[mi][ni] = __builtin_amdgcn_mfma_f32_16x16x32_bf16(afr[mi], bfr[ni], acc[mi][ni], 0, 0, 0);
        __syncthreads();
    }

#pragma unroll
    for (int ni = 0; ni < 4; ni++) {
        int col = colBase + wc * 64 + ni * 16 + lane15;   // dout
        float bias = bia[col];
        int h = col >> 6, dk = col & 63;
#pragma unroll
        for (int mi = 0; mi < 4; mi++) {
#pragma unroll
            for (int r = 0; r < 4; r++) {
                int row = rowBase + wr * 64 + mi * 16 + quad * 4 + r;
                int b = row >> 11, l = row & 2047;
                float v = acc[mi][ni][r] + bias;
                size_t dst = (z < 2) ? ((((size_t)(b * 16 + h)) * 2048 + l) * 64 + dk)
                                     : ((((size_t)(b * 16 + h)) * 64 + dk) * 2048 + l);
                out[dst] = (bf16_t)v;
            }
        }
    }
}

// ---------------------------------------------------------------------------
// Output projection: A (concat) bf16, Bt (woT) bf16, out f32.
// 128x64 tile -> 512 blocks. m97 DMA staging, unpadded layout.
// ---------------------------------------------------------------------------
__global__ __launch_bounds__(256, 2) void gemm_out_kernel(
    const bf16_t* __restrict__ A, const bf16_t* __restrict__ Bt,
    const float* __restrict__ bia, float* __restrict__ out)
{
    __shared__ bf16_t As[128 * 32];     // 8 KB
    __shared__ bf16_t Bs[64 * 32];      // 4 KB
    const int t = threadIdx.x;
    const int w = t >> 6, lane = t & 63;
    const int lane15 = lane & 15, quad = lane >> 4;
    const int wr = w >> 1, wc = w & 1;
    const int rowBase = blockIdx.x * 128, colBase = blockIdx.y * 64;

    const int brow = lane >> 2, bcol = (lane & 3) * 8;  // bf16 chunk map

    f32x4 acc[4][2];
    f32x4 zf = {0.f, 0.f, 0.f, 0.f};
#pragma unroll
    for (int i = 0; i < 4; i++)
#pragma unroll
        for (int j = 0; j < 2; j++) acc[i][j] = zf;

    for (int k0 = 0; k0 < 1024; k0 += 32) {
#pragma unroll
        for (int j = 0; j < 2; j++) {   // 2 A-chunks per wave
            int chunk = w * 2 + j;
            load_lds16(A + (size_t)(rowBase + chunk * 16 + brow) * 1024 + k0 + bcol,
                       (char*)As + chunk * 1024);
        }
        {                               // 1 B-chunk per wave
            int chunk = w;
            load_lds16(Bt + (size_t)(colBase + chunk * 16 + brow) * 1024 + k0 + bcol,
                       (char*)Bs + chunk * 1024);
        }
        __syncthreads();
        bf16x8 afr[4], bfr[2];
#pragma unroll
        for (int mi = 0; mi < 4; mi++)
            afr[mi] = *(const bf16x8*)(As + (wr * 64 + mi * 16 + lane15) * 32 + quad * 8);
#pragma unroll
        for (int ni = 0; ni < 2; ni++)
            bfr[ni] = *(const bf16x8*)(Bs + (wc * 32 + ni * 16 + lane15) * 32 + quad * 8);
#pragma unroll
        for (int mi = 0; mi < 4; mi++)
#pragma unroll
            for (int ni = 0; ni < 2; ni++)
                acc[mi][ni] = __builtin_amdgcn_mfma_f32_16x16x32_bf16(afr[mi], bfr[ni], acc[mi][ni], 0, 0, 0);
        __syncthreads();
    }

#pragma unroll
    for (int ni = 0; ni < 2; ni++) {
        int col = colBase + wc * 32 + ni * 16 + lane15;
        float bias = bia[col];
#pragma unroll
        for (int mi = 0; mi < 4; mi++) {
#pragma unroll
            for (int r = 0; r < 4; r++) {
                int row = rowBase + wr * 64 + mi * 16 + quad * 4 + r;
                out[(size_t)row * 1024 + col] = acc[mi][ni][r] + bias;
            }
        }
    }
}

// ---------------------------------------------------------------------------
// Flash attention v4: LDS-staged K/V (double-buffered) with 32 q-rows/wave
// and TRANSPOSED scores (S^T = K*Q^T) so P is written packed b64 in A-operand
// order. Row-sums via ones-MFMA. Fixed-max exp2 softmax. Block = 128 q-rows.
// XCD swizzle: blockIdx.x = bh.
// Q,K bf16 [B,H,L,DK]; V bf16 [B,H,DK,L]. attn out [B,L,H,DK].
// ---------------------------------------------------------------------------
#define FS 72   // LDS row stride (bf16): 144 B = 16B-aligned, non-pow2 banks

__global__ __launch_bounds__(256, 2) void flash_kernel(
    const bf16_t* __restrict__ QKV, const int* __restrict__ mask,
    const int* __restrict__ flags, bf16_t* __restrict__ attnout)
{
    __shared__ bf16_t Ks[2][64 * FS];
    __shared__ bf16_t Vs[2][64 * FS];
    __shared__ bf16_t Ps[8 * 16 * FS];      // 4 waves x 2 q-subtiles
    const int t = threadIdx.x, w = t >> 6, lane = t & 63;
    const int lane15 = lane & 15, quad = lane >> 4;
    const int qt = blockIdx.y, bh = blockIdx.x;   // swizzled
    const int b = bh >> 4, h = bh & 15;
    const bf16_t* Q  = QKV;
    const bf16_t* K  = QKV + 4194304;
    const bf16_t* Vt = QKV + 8388608;
    const int qrow0 = qt * 128 + w * 32;

    bf16x8 aq[2][2];
#pragma unroll
    for (int qf = 0; qf < 2; qf++) {
        const bf16_t* qb = Q + ((size_t)bh * 2048 + qrow0 + qf * 16 + lane15) * 64;
        aq[qf][0] = *(const bf16x8*)(qb + quad * 8);
        aq[qf][1] = *(const bf16x8*)(qb + 32 + quad * 8);
#pragma unroll
        for (int j = 0; j < 8; j++) {   // exact: *2^-3
            aq[qf][0][j] = (bf16_t)((float)aq[qf][0][j] * 0.125f);
            aq[qf][1][j] = (bf16_t)((float)aq[qf][1][j] * 0.125f);
        }
    }

    f32x4 zf = {0.f, 0.f, 0.f, 0.f};
    f32x4 o[2][4];
#pragma unroll
    for (int qf = 0; qf < 2; qf++)
#pragma unroll
        for (int df = 0; df < 4; df++) o[qf][df] = zf;
    f32x4 lsum[2] = {zf, zf};
    bf16_t* Pw0 = Ps + (w * 2 + 0) * 16 * FS;
    bf16_t* Pw1 = Ps + (w * 2 + 1) * 16 * FS;
    bf16x8 ones;
#pragma unroll
    for (int j = 0; j < 8; j++) ones[j] = (bf16_t)1.0f;

    const int e0 = t * 8, e1 = (256 + t) * 8;
    const int kr0 = e0 >> 6, kc0 = e0 & 63, kr1 = e1 >> 6, kc1 = e1 & 63;
    const int* flagrow = flags + (b * 32 + qt) * 32;
    const bf16_t* Kb  = K  + (size_t)bh * 131072;
    const bf16_t* Vtb = Vt + (size_t)bh * 131072;

    {
        bf16x8 k0v = *(const bf16x8*)(Kb  + (size_t)kr0 * 64 + kc0);
        bf16x8 k1v = *(const bf16x8*)(Kb  + (size_t)kr1 * 64 + kc1);
        bf16x8 v0v = *(const bf16x8*)(Vtb + (size_t)kr0 * 2048 + kc0);
        bf16x8 v1v = *(const bf16x8*)(Vtb + (size_t)kr1 * 2048 + kc1);
        *(bf16x8*)(Ks[0] + kr0 * FS + kc0) = k0v;
        *(bf16x8*)(Ks[0] + kr1 * FS + kc1) = k1v;
        *(bf16x8*)(Vs[0] + kr0 * FS + kc0) = v0v;
        *(bf16x8*)(Vs[0] + kr1 * FS + kc1) = v1v;
    }
    __syncthreads();

    for (int kt = 0; kt < 32; kt++) {
        const int cur = kt & 1, nxt = cur ^ 1;
        bf16x8 k0v, k1v, v0v, v1v;
        if (kt + 1 < 32) {
            int kn = (kt + 1) * 64;
            k0v = *(const bf16x8*)(Kb  + (size_t)(kn + kr0) * 64 + kc0);
            k1v = *(const bf16x8*)(Kb  + (size_t)(kn + kr1) * 64 + kc1);
            v0v = *(const bf16x8*)(Vtb + (size_t)kr0 * 2048 + kn + kc0);
            v1v = *(const bf16x8*)(Vtb + (size_t)kr1 * 2048 + kn + kc1);
        }

        f32x4 st[2][4];
#pragma unroll
        for (int kf = 0; kf < 4; kf++) {
            bf16x8 kb0 = *(const bf16x8*)(Ks[cur] + (kf * 16 + lane15) * FS + quad * 8);
            bf16x8 kb1 = *(const bf16x8*)(Ks[cur] + (kf * 16 + lane15) * FS + 32 + quad * 8);
#pragma unroll
            for (int qf = 0; qf < 2; qf++) {
                f32x4 a = zf;
                a = __builtin_amdgcn_mfma_f32_16x16x32_bf16(kb0, aq[qf][0], a, 0, 0, 0);
                a = __builtin_amdgcn_mfma_f32_16x16x32_bf16(kb1, aq[qf][1], a, 0, 0, 0);
                st[qf][kf] = a * 1.44269504f;
            }
        }
        if (kt + 1 < 32) {
            *(bf16x8*)(Ks[nxt] + kr0 * FS + kc0) = k0v;
            *(bf16x8*)(Ks[nxt] + kr1 * FS + kc1) = k1v;
            *(bf16x8*)(Vs[nxt] + kr0 * FS + kc0) = v0v;
            *(bf16x8*)(Vs[nxt] + kr1 * FS + kc1) = v1v;
        }
        if (!flagrow[kt]) {
#pragma unroll
            for (int qf = 0; qf < 2; qf++)
#pragma unroll
                for (int kf = 0; kf < 4; kf++)
#pragma unroll
                    for (int r = 0; r < 4; r++) {
                        int qrow = qrow0 + qf * 16 + lane15;
                        int kpos = kt * 64 + kf * 16 + quad * 4 + r;
                        if (mask[((size_t)b * 2048 + qrow) * 2048 + kpos] == 0)
                            st[qf][kf][r] = -1e30f;
                    }
        }
#pragma unroll
        for (int qf = 0; qf < 2; qf++) {
            bf16_t* Pq = qf ? Pw1 : Pw0;
#pragma unroll
            for (int kf = 0; kf < 4; kf++) {
                bf16x4 pv;
#pragma unroll
                for (int r = 0; r < 4; r++) pv[r] = (bf16_t)exp2f(st[qf][kf][r]);
                *(bf16x4*)(Pq + lane15 * FS + kf * 16 + quad * 4) = pv;
            }
        }
        bf16x8 pa[2][2];
        pa[0][0] = *(const bf16x8*)(Pw0 + lane15 * FS + quad * 8);
        pa[0][1] = *(const bf16x8*)(Pw0 + lane15 * FS + 32 + quad * 8);
        pa[1][0] = *(const bf16x8*)(Pw1 + lane15 * FS + quad * 8);
        pa[1][1] = *(const bf16x8*)(Pw1 + lane15 * FS + 32 + quad * 8);
#pragma unroll
        for (int qf = 0; qf < 2; qf++) {
            lsum[qf] = __builtin_amdgcn_mfma_f32_16x16x32_bf16(ones, pa[qf][0], lsum[qf], 0, 0, 0);
            lsum[qf] = __builtin_amdgcn_mfma_f32_16x16x32_bf16(ones, pa[qf][1], lsum[qf], 0, 0, 0);
        }
#pragma unroll
        for (int df = 0; df < 4; df++) {
            bf16x8 vb0 = *(const bf16x8*)(Vs[cur] + (df * 16 + lane15) * FS + quad * 8);
            bf16x8 vb1 = *(const bf16x8*)(Vs[cur] + (df * 16 + lane15) * FS + 32 + quad * 8);
#pragma unroll
            for (int qf = 0; qf < 2; qf++) {
                o[qf][df] = __builtin_amdgcn_mfma_f32_16x16x32_bf16(pa[qf][0], vb0, o[qf][df], 0, 0, 0);
                o[qf][df] = __builtin_amdgcn_mfma_f32_16x16x32_bf16(pa[qf][1], vb1, o[qf][df], 0, 0, 0);
            }
        }
        __syncthreads();
    }

#pragma unroll
    for (int qf = 0; qf < 2; qf++) {
        float lv = lsum[qf][0];
#pragma unroll
        for (int r = 0; r < 4; r++) {
            float inv = 1.0f / __shfl(lv, quad * 4 + r, 64);
            size_t row = (size_t)b * 2048 + qrow0 + qf * 16 + quad * 4 + r;
#pragma unroll
            for (int df = 0; df < 4; df++)
                attnout[(row * 16 + h) * 64 + df * 16 + lane15] = (bf16_t)(o[qf][df][r] * inv);
        }
    }
}

// ---------------------------------------------------------------------------
// Inter-head attention: one wave per position (b,l). attn is [B,L,H,DK].
// ---------------------------------------------------------------------------
__global__ __launch_bounds__(256, 2) void interhead_kernel(
    const bf16_t* __restrict__ attn,
    const bf16_t* __restrict__ whqT, const float* __restrict__ bhq,
    const bf16_t* __restrict__ whkT, const float* __restrict__ bhk,
    const bf16_t* __restrict__ whvT, const float* __restrict__ bhv,
    bf16_t* __restrict__ concat)
{
    __shared__ bf16_t lds[4 * 4608];
    const int t = threadIdx.x, w = t >> 6, lane = t & 63;
    const int lane15 = lane & 15, quad = lane >> 4;
    bf16_t* Qh  = lds + w * 4608;   // [16][64]
    bf16_t* Kh  = Qh + 1024;        // [16][64]
    bf16_t* VhT = Kh + 1024;        // [64][32] (k-padded)
    bf16_t* P16 = VhT + 2048;       // [16][32] (k-padded)
    const int p = blockIdx.x * 4 + w;

    bf16x8 z8 = {(bf16_t)0.f, (bf16_t)0.f, (bf16_t)0.f, (bf16_t)0.f,
                 (bf16_t)0.f, (bf16_t)0.f, (bf16_t)0.f, (bf16_t)0.f};
    ((bf16x8*)P16)[lane] = z8;
#pragma unroll
    for (int i = 0; i < 4; i++) ((bf16x8*)VhT)[i * 64 + lane] = z8;

    const bf16_t* hb = attn + ((size_t)p * 16 + lane15) * 64;
    bf16x8 ha0 = *(const bf16x8*)(hb + quad * 8);
    bf16x8 ha1 = *(const bf16x8*)(hb + 32 + quad * 8);

    const bf16_t* Wt[3] = {whqT, whkT, whvT};
    const float*  Bb[3] = {bhq, bhk, bhv};
    f32x4 zf = {0.f, 0.f, 0.f, 0.f};
#pragma unroll
    for (int m3 = 0; m3 < 3; m3++) {
#pragma unroll
        for (int nf = 0; nf < 4; nf++) {
            f32x4 acc = zf;
            bf16x8 wb0 = *(const bf16x8*)(Wt[m3] + (nf * 16 + lane15) * 64 + quad * 8);
            bf16x8 wb1 = *(const bf16x8*)(Wt[m3] + (nf * 16 + lane15) * 64 + 32 + quad * 8);
            acc = __builtin_amdgcn_mfma_f32_16x16x32_bf16(ha0, wb0, acc, 0, 0, 0);
            acc = __builtin_amdgcn_mfma_f32_16x16x32_bf16(ha1, wb1, acc, 0, 0, 0);
            float bias = Bb[m3][nf * 16 + lane15];
#pragma unroll
            for (int r = 0; r < 4; r++) {
                float v = acc[r] + bias;
                if (m3 == 0) v *= 0.125f;   // fold inter scale into Qh (exact)
                if (m3 == 2) VhT[(nf * 16 + lane15) * 32 + quad * 4 + r] = (bf16_t)v;
                else if (m3 == 0) Qh[(quad * 4 + r) * 64 + nf * 16 + lane15] = (bf16_t)v;
                else Kh[(quad * 4 + r) * 64 + nf * 16 + lane15] = (bf16_t)v;
            }
        }
    }
    __syncthreads();

    bf16x8 qa0 = *(const bf16x8*)(Qh + lane15 * 64 + quad * 8);
    bf16x8 qa1 = *(const bf16x8*)(Qh + lane15 * 64 + 32 + quad * 8);
    bf16x8 kb0 = *(const bf16x8*)(Kh + lane15 * 64 + quad * 8);
    bf16x8 kb1 = *(const bf16x8*)(Kh + lane15 * 64 + 32 + quad * 8);
    f32x4 s = zf;
    s = __builtin_amdgcn_mfma_f32_16x16x32_bf16(qa0, kb0, s, 0, 0, 0);
    s = __builtin_amdgcn_mfma_f32_16x16x32_bf16(qa1, kb1, s, 0, 0, 0);
#pragma unroll
    for (int r = 0; r < 4; r++) {
        float v = s[r];
        float mx = v;
        mx = fmaxf(mx, __shfl_xor(mx, 1));
        mx = fmaxf(mx, __shfl_xor(mx, 2));
        mx = fmaxf(mx, __shfl_xor(mx, 4));
        mx = fmaxf(mx, __shfl_xor(mx, 8));
        float pv = __expf(v - mx);
        float sm = pv;
        sm += __shfl_xor(sm, 1);
        sm += __shfl_xor(sm, 2);
        sm += __shfl_xor(sm, 4);
        sm += __shfl_xor(sm, 8);
        P16[(quad * 4 + r) * 32 + lane15] = (bf16_t)(pv / sm);
    }
    __syncthreads();

    bf16x8 pa = *(const bf16x8*)(P16 + lane15 * 32 + quad * 8);
    bf16_t* outp = concat + (size_t)p * 1024;
#pragma unroll
    for (int df = 0; df < 4; df++) {
        bf16x8 vb = *(const bf16x8*)(VhT + (df * 16 + lane15) * 32 + quad * 8);
        f32x4 mix = zf;
        mix = __builtin_amdgcn_mfma_f32_16x16x32_bf16(pa, vb, mix, 0, 0, 0);
#pragma unroll
        for (int r = 0; r < 4; r++)
            outp[(quad * 4 + r) * 64 + df * 16 + lane15] = (bf16_t)mix[r];
    }
}

// ---------------------------------------------------------------------------
extern "C" void kernel_launch(void* const* d_in, const int* in_sizes, int n_in,
                              void* d_out, int out_size, void* d_ws, size_t ws_size,
                              hipStream_t stream)
{
    const float* q_in = (const float*)d_in[0];
    const float* k_in = (const float*)d_in[1];
    const float* v_in = (const float*)d_in[2];
    const int*   mask = (const int*)d_in[3];
    const float* wq = (const float*)d_in[4];
    const float* bq = (const float*)d_in[5];
    const float* wk = (const float*)d_in[6];
    const float* bk = (const float*)d_in[7];
    const float* wv = (const float*)d_in[8];
    const float* bv = (const float*)d_in[9];
    const float* wo = (const float*)d_in[10];
    const float* bo = (const float*)d_in[11];
    const float* whq = (const float*)d_in[12];
    const float* bhq = (const float*)d_in[13];
    const float* whk = (const float*)d_in[14];
    const float* bhk = (const float*)d_in[15];
    const float* whv = (const float*)d_in[16];
    const float* bhv = (const float*)d_in[17];
    float* out = (float*)d_out;         // [4096][1024] f32 = 16 MB

    char* ws = (char*)d_ws;
    bf16_t* qkvb  = (bf16_t*)ws;                       // 24 MB: Q|K|Vt
    bf16_t* concat = qkvb;                             // Q region, post-flash
    bf16_t* woT   = (bf16_t*)(ws + 8u * 1024 * 1024);  // K region, post-flash
    bf16_t* whqT  = (bf16_t*)(ws + 10u * 1024 * 1024);
    bf16_t* whkT  = whqT + 4096;
    bf16_t* whvT  = whqT + 8192;
    bf16_t* attnb = (bf16_t*)d_out;                    // 8 MB bf16 in d_out
    bf16_t* wqkvT = (bf16_t*)((char*)d_out + 8u * 1024 * 1024);
    int*    flags = (int*)((char*)d_out + 14u * 1024 * 1024);

    prep1_kernel<<<2816, 256, 0, stream>>>(mask, flags, wq, wk, wv, wqkvT);
    gemm_qkv_kernel<<<dim3(32, 8, 3), 256, 0, stream>>>(q_in, k_in, v_in, wqkvT, bq, bk, bv, qkvb);
    flash_kernel<<<dim3(32, 16), 256, 0, stream>>>(qkvb, mask, flags, attnb);
    prep2_kernel<<<259, 256, 0, stream>>>(wo, woT, whq, whk, whv, whqT, whkT, whvT);
    interhead_kernel<<<1024, 256, 0, stream>>>(attnb, whqT, bhq, whkT, bhk, whvT, bhv, concat);
    gemm_out_kernel<<<dim3(32, 16), 256, 0, stream>>>(concat, woT, bo, out);
    (void)in_sizes; (void)n_in; (void)out_size; (void)ws_size;
}